// Round 1
// baseline (138.794 us; speedup 1.0000x reference)
//
#include <hip/hip_runtime.h>

#define NL   128   // rows per line table
#define CL   32    // channels per line table
#define HDIM 128   // hidden dim

// ws layout: unsigned long long gmask[6] = {x_lo, x_hi, y_lo, y_hi, z_lo, z_hi}

__global__ __launch_bounds__(256) void mask_fill_kernel(
    const float* __restrict__ coords, long long nflt,
    const float* __restrict__ b1, const float* __restrict__ w2,
    const float* __restrict__ b2,
    unsigned long long* __restrict__ gmask,
    float* __restrict__ out, int out_n)
{
    const int tid = threadIdx.x;
    const int gid = blockIdx.x * blockDim.x + tid;
    const int nthreads = gridDim.x * blockDim.x;
    const int lane = tid & 63;
    const int wave = tid >> 6;

    unsigned long long mx0 = 0, mx1 = 0, my0 = 0, my1 = 0, mz0 = 0, mz1 = 0;

    const float4* c4 = (const float4*)coords;
    const long long n4 = nflt >> 2;            // number of float4s
    const long long n4tri = (n4 / 3) * 3;      // full 3-float4 (12-float) groups

    // Each thread consumes 3 consecutive float4s (= 4 xyz triples) per iter,
    // so the dim of element e is the compile-time constant e % 3.
    for (long long base = (long long)gid * 3; base + 2 < n4tri;
         base += (long long)nthreads * 3) {
        float4 a = c4[base + 0];
        float4 b = c4[base + 1];
        float4 c = c4[base + 2];
        float v[12] = {a.x, a.y, a.z, a.w, b.x, b.y, b.z, b.w, c.x, c.y, c.z, c.w};
        #pragma unroll
        for (int e = 0; e < 12; ++e) {
            float fi = rintf((v[e] + 2.0f) * 32.0f);   // (x + D/2) * (Nl/D), half-to-even
            bool valid = (fi >= 0.0f) && (fi < 128.0f);
            int idx = (int)fi;
            unsigned long long bit = 1ull << (idx & 63);
            unsigned long long blo = (valid && idx < 64) ? bit : 0ull;
            unsigned long long bhi = (valid && idx >= 64) ? bit : 0ull;
            if (e % 3 == 0)      { mx0 |= blo; mx1 |= bhi; }
            else if (e % 3 == 1) { my0 |= blo; my1 |= bhi; }
            else                 { mz0 |= blo; mz1 |= bhi; }
        }
    }
    // Tail (not hit for the fixed problem size, kept for robustness).
    for (long long f = n4tri * 4 + gid; f < nflt; f += nthreads) {
        float fi = rintf((coords[f] + 2.0f) * 32.0f);
        bool valid = (fi >= 0.0f) && (fi < 128.0f);
        int idx = (int)fi;
        unsigned long long bit = 1ull << (idx & 63);
        unsigned long long blo = (valid && idx < 64) ? bit : 0ull;
        unsigned long long bhi = (valid && idx >= 64) ? bit : 0ull;
        int d = (int)(f % 3);
        if (d == 0)      { mx0 |= blo; mx1 |= bhi; }
        else if (d == 1) { my0 |= blo; my1 |= bhi; }
        else             { mz0 |= blo; mz1 |= bhi; }
    }

    // Butterfly OR-reduce across the 64-lane wave.
    #pragma unroll
    for (int off = 1; off < 64; off <<= 1) {
        mx0 |= __shfl_xor(mx0, off);
        mx1 |= __shfl_xor(mx1, off);
        my0 |= __shfl_xor(my0, off);
        my1 |= __shfl_xor(my1, off);
        mz0 |= __shfl_xor(mz0, off);
        mz1 |= __shfl_xor(mz1, off);
    }

    __shared__ unsigned long long sm[4][6];
    if (lane == 0) {
        sm[wave][0] = mx0; sm[wave][1] = mx1;
        sm[wave][2] = my0; sm[wave][3] = my1;
        sm[wave][4] = mz0; sm[wave][5] = mz1;
    }
    __syncthreads();
    if (tid < 6) {
        unsigned long long r = sm[0][tid] | sm[1][tid] | sm[2][tid] | sm[3][tid];
        atomicOr(&gmask[tid], r);
    }

    // Constant for rows >= NL: b2 + sum_j relu(b1[j]) * w2[j]
    float p = fmaxf(b1[lane], 0.0f) * w2[lane]
            + fmaxf(b1[lane + 64], 0.0f) * w2[lane + 64];
    #pragma unroll
    for (int off = 1; off < 64; off <<= 1) p += __shfl_xor(p, off);
    const float constant = p + b2[0];

    // Fill out[NL..out_n) with the constant (float4 stores; NL % 4 == 0).
    const int n4o = (out_n - NL) >> 2;
    float4* o4 = (float4*)(out + NL);
    const float4 cv = make_float4(constant, constant, constant, constant);
    for (int i = gid; i < n4o; i += nthreads) o4[i] = cv;
    for (int i = NL + (n4o << 2) + gid; i < out_n; i += nthreads) out[i] = constant;
}

__global__ __launch_bounds__(512) void head_kernel(
    const float* __restrict__ l0, const float* __restrict__ l1,
    const float* __restrict__ l2,
    const float* __restrict__ w1, const float* __restrict__ b1,
    const float* __restrict__ w2, const float* __restrict__ b2,
    const unsigned long long* __restrict__ gmask, float* __restrict__ out)
{
    const int gtid = blockIdx.x * blockDim.x + threadIdx.x;  // 0..1023
    const int r = gtid >> 3;   // row 0..127
    const int g = gtid & 7;    // 8 threads per row
    if (r >= NL) return;

    const int word = r >> 6;
    const int bit = r & 63;
    const float ox = (float)((gmask[0 + word] >> bit) & 1ull);
    const float oy = (float)((gmask[2 + word] >> bit) & 1ull);
    const float oz = (float)((gmask[4 + word] >> bit) & 1ull);

    const float R  = 0.4f;
    const float R2 = (float)(0.4 * 0.4);   // matches Python RANGE**2 rounded to f32

    float feats[CL];
    #pragma unroll
    for (int c = 0; c < CL; ++c) {
        float x = l0[r * CL + c] * ox;
        float y = l1[r * CL + c] * oy;
        float z = l2[r * CL + c] * oz;
        float f1 = x + y + z;
        float f2 = (x * y + x * z + y * z) / R;
        float f3 = x * y * z / R2;
        feats[c] = f1 + f2 + f3;
    }

    float partial = 0.0f;
    #pragma unroll 4
    for (int j = g; j < HDIM; j += 8) {
        float acc = b1[j];
        #pragma unroll
        for (int c = 0; c < CL; ++c) acc += feats[c] * w1[j * CL + c];
        partial += fmaxf(acc, 0.0f) * w2[j];
    }
    // reduce over the 8-thread group (aligned inside the wave)
    partial += __shfl_xor(partial, 1);
    partial += __shfl_xor(partial, 2);
    partial += __shfl_xor(partial, 4);
    if (g == 0) out[r] = partial + b2[0];
}

extern "C" void kernel_launch(void* const* d_in, const int* in_sizes, int n_in,
                              void* d_out, int out_size, void* d_ws, size_t ws_size,
                              hipStream_t stream) {
    const float* coords = (const float*)d_in[0];
    const float* l0 = (const float*)d_in[1];
    const float* l1 = (const float*)d_in[2];
    const float* l2 = (const float*)d_in[3];
    const float* w1 = (const float*)d_in[4];
    const float* b1 = (const float*)d_in[5];
    const float* w2 = (const float*)d_in[6];
    const float* b2 = (const float*)d_in[7];
    float* out = (float*)d_out;
    unsigned long long* gmask = (unsigned long long*)d_ws;
    const long long nflt = (long long)in_sizes[0];

    hipMemsetAsync(d_ws, 0, 6 * sizeof(unsigned long long), stream);
    mask_fill_kernel<<<1024, 256, 0, stream>>>(coords, nflt, b1, w2, b2,
                                               gmask, out, out_size);
    head_kernel<<<2, 512, 0, stream>>>(l0, l1, l2, w1, b1, w2, b2, gmask, out);
}